// Round 10
// baseline (140.661 us; speedup 1.0000x reference)
//
#include <hip/hip_runtime.h>

#define HH 192
#define WW 256
#define TH 8
#define TW 32
#define CCH 4            // channels per chunk
#define NCHUNK 16        // 64 / 4
#define THREADS 576      // 9 waves; wave w handles i = w - 4
#define CHSTEP (CCH * HH * WW)

typedef float f4 __attribute__((ext_vector_type(4)));
typedef int   i4 __attribute__((ext_vector_type(4)));

// async global->LDS, 16B per lane, dest = wave-uniform base + lane*16
#define GLL(gp, lp) __builtin_amdgcn_global_load_lds(                        \
    (const __attribute__((address_space(1))) unsigned int*)(gp),            \
    (__attribute__((address_space(3))) unsigned int*)(lp), 16, 0, 0)

// quad_perm DPP: dst lane 4k+q gets src lane 4k+e_q. Position-absolute,
// no direction ambiguity. CTRL = e0|e1<<2|e2<<4|e3<<6.
#define DPP4(dst, srcf, CTRL)                                                \
    {                                                                        \
        const i4 s_ = __builtin_bit_cast(i4, srcf);                          \
        i4 d_;                                                               \
        d_[0] = __builtin_amdgcn_update_dpp(0, s_[0], (CTRL), 0xF, 0xF, 1);  \
        d_[1] = __builtin_amdgcn_update_dpp(0, s_[1], (CTRL), 0xF, 0xF, 1);  \
        d_[2] = __builtin_amdgcn_update_dpp(0, s_[2], (CTRL), 0xF, 0xF, 1);  \
        d_[3] = __builtin_amdgcn_update_dpp(0, s_[3], (CTRL), 0xF, 0xF, 1);  \
        dst = __builtin_bit_cast(f4, d_);                                    \
    }

// smem layout (floats, linear in staged-unit order) — R8 layout, swizzle
// reverted (R9: XOR swizzle RAISED conflicts 1.06e7 -> 1.81e7):
//   s1: [2 buf][4 ch][8 rows][32 cols]         = 2048 floats @ 0
//   s2: [2 buf][4 ch][16 rows][16 units x 16B] = 8192 floats @ 2048
// R10: x2 window sharing. Lane reads only its CENTER unit (wcg+1); left /
// right units come from quad neighbors via quad_perm DPP (VALU pipe).
// Quad-edge lanes (wcg&3==0 / ==3) fetch their edge unit (wcg / wcg+2)
// with one half-active read. LDS banked bytes: 4KB -> 2.5KB per cc.
__global__ __launch_bounds__(THREADS) void cost_volume_kernel(
    const float* __restrict__ x1, const float* __restrict__ x2,
    float* __restrict__ out)
{
    __shared__ __align__(16) float smem[10240];

    const int tid  = threadIdx.x;
    const int wave = tid >> 6;      // 0..8 -> i = wave - 4
    const int lane = tid & 63;
    const int r    = lane >> 3;     // 0..7 tile row
    const int wcg  = lane & 7;      // 0..7 col group (4 px each)

    const int bid = blockIdx.x;
    const int b   = bid / 192;      // 24 h-tiles * 8 w-tiles
    const int rem = bid % 192;
    const int h0  = (rem >> 3) * TH;
    const int w0  = (rem & 7) * TW;

    // ---- x2 staging: [4 ch][16 rows][16 units/row] = 1024 units/chunk ----
    // unit u: ch=u>>8, row=(u>>4)&15, cu=u&15 (col=cu*4; cu<=9 is data).
    // 16 GLL/chunk: wave w does strip w (all 9) and strip w+9 (waves 0..6).
    auto desc2 = [&](int u, bool& v, long& goff) {
        const int ch = u >> 8, row = (u >> 4) & 15, cu = u & 15;
        const int hg = h0 - 4 + row, wg = w0 - 4 + cu * 4;
        v = (cu <= 9) & (hg >= 0) & (hg < HH) & (wg >= 0) & (wg <= WW - 4);
        goff = ((long)(b * 64 + ch) * HH + hg) * WW + wg;
    };
    bool vA, vB0; long gA, gB;
    desc2((wave << 6) + lane, vA, gA);
    desc2(((wave + 9) << 6) + lane, vB0, gB);
    const bool vB = vB0 & (wave <= 6);

    // ---- x1 staging: [4 ch][8 rows][8 units/row] = 256 units/chunk ----
    // waves 1..4, one GLL each. Lane->dword is perfectly linear: 0 conflicts.
    const bool v1 = (wave >= 1) & (wave <= 4);
    const int w1 = (wave - 1) & 7;
    const int u1 = (w1 << 6) + lane;
    const int ch1 = u1 >> 6, r1 = (u1 >> 3) & 7, c1 = (u1 & 7) * 4;
    const long g1 = ((long)(b * 64 + ch1) * HH + (h0 + r1)) * WW + (w0 + c1);

    auto issue = [&](int nb, int n) {
        const long cofs = (long)n * CHSTEP;
        float* const b2 = smem + 2048 + nb * 4096;
        float* const b1 = smem + nb * 1024;
        if (vA) GLL(x2 + gA + cofs, b2 + (wave << 8));
        if (vB) GLL(x2 + gB + cofs, b2 + ((wave + 9) << 8));
        if (v1) GLL(x1 + g1 + cofs, b1 + (w1 << 8));
    };

    // ---- pre-zero LDS: pad/OOB slots are never written by masked lanes ----
    const f4 z4 = {0.f, 0.f, 0.f, 0.f};
    for (int z = tid; z < 10240 / 4; z += THREADS) ((f4*)smem)[z] = z4;
    __syncthreads();

    issue(0, 0);
    __syncthreads();   // drains vmcnt(0) before s_barrier

    f4 acc0 = z4, acc1 = z4, acc2 = z4, acc3 = z4, acc4 = z4,
       acc5 = z4, acc6 = z4, acc7 = z4, acc8 = z4;

    const int row2 = r + 8 - wave;           // x2 halo row, in [0,15]
    const bool bl = (wcg & 3) == 0;          // quad-left edge lane
    const bool br = (wcg & 3) == 3;          // quad-right edge lane
    const bool bedge = bl | br;
    const int eoff = (bl ? wcg : wcg + 2) * 4;  // edge unit dword offset

    for (int n = 0; n < NCHUNK; ++n) {
        if (n + 1 < NCHUNK) issue((n + 1) & 1, n + 1);
        const float* sb1 = smem + (n & 1) * 1024 + r * 32 + wcg * 4;
        const float* sb2 = smem + 2048 + (n & 1) * 4096 + row2 * 64;
#pragma unroll
        for (int cc = 0; cc < CCH; ++cc) {
            const float* sb2c = sb2 + cc * 1024;
            const f4 av = *(const f4*)(sb1 + cc * 256);
            const f4 xv1 = *(const f4*)(sb2c + (wcg + 1) * 4);  // center unit
            f4 ex;
            if (bedge) ex = *(const f4*)(sb2c + eoff);          // half-active
            f4 xl, xr;
            DPP4(xl, xv1, 0x90);   // quad_perm [0,0,1,2]: lane q <- q-1
            DPP4(xr, xv1, 0xF9);   // quad_perm [1,2,3,3]: lane q <- q+1
            const f4 xv0 = bl ? ex : xl;   // unit wcg
            const f4 xv2 = br ? ex : xr;   // unit wcg+2
            // out px p needs halo col wcg*4 + p + 8 - jj  (p=0..3)
            const f4 w8 = xv0;
            const f4 w7 = __builtin_shufflevector(xv0, xv1, 1, 2, 3, 4);
            const f4 w6 = __builtin_shufflevector(xv0, xv1, 2, 3, 4, 5);
            const f4 w5 = __builtin_shufflevector(xv0, xv1, 3, 4, 5, 6);
            const f4 w4 = xv1;
            const f4 w3 = __builtin_shufflevector(xv1, xv2, 1, 2, 3, 4);
            const f4 w2 = __builtin_shufflevector(xv1, xv2, 2, 3, 4, 5);
            const f4 w1w = __builtin_shufflevector(xv1, xv2, 3, 4, 5, 6);
            const f4 w0w = xv2;
            acc0 = __builtin_elementwise_fma(av, w0w, acc0);
            acc1 = __builtin_elementwise_fma(av, w1w, acc1);
            acc2 = __builtin_elementwise_fma(av, w2, acc2);
            acc3 = __builtin_elementwise_fma(av, w3, acc3);
            acc4 = __builtin_elementwise_fma(av, w4, acc4);
            acc5 = __builtin_elementwise_fma(av, w5, acc5);
            acc6 = __builtin_elementwise_fma(av, w6, acc6);
            acc7 = __builtin_elementwise_fma(av, w7, acc7);
            acc8 = __builtin_elementwise_fma(av, w8, acc8);
        }
        __syncthreads();
    }

    // ---- epilogue ----
    const float scale = 1.0f / 81.0f;
    const int hout = h0 + r;
    const int wout = w0 + wcg * 4;
    // k = (9*i + j) mod 81 = (9*wave + jj + 41) mod 81
#define CV_OUT(JJ)                                                           \
    {                                                                        \
        const int k = (9 * wave + (JJ) + 41) % 81;                           \
        float* po = out + (((long)b * 81 + k) * HH + hout) * WW + wout;      \
        *(f4*)po = acc##JJ * scale;                                          \
    }
    CV_OUT(0) CV_OUT(1) CV_OUT(2) CV_OUT(3) CV_OUT(4)
    CV_OUT(5) CV_OUT(6) CV_OUT(7) CV_OUT(8)
#undef CV_OUT
}

extern "C" void kernel_launch(void* const* d_in, const int* in_sizes, int n_in,
                              void* d_out, int out_size, void* d_ws, size_t ws_size,
                              hipStream_t stream) {
    const float* x1 = (const float*)d_in[0];
    const float* x2 = (const float*)d_in[1];
    float* out = (float*)d_out;
    dim3 grid(8 * 24 * 8);   // 1536 blocks
    dim3 block(THREADS);
    hipLaunchKernelGGL(cost_volume_kernel, grid, block, 0, stream, x1, x2, out);
}

// Round 11
// 112.463 us; speedup vs baseline: 1.2507x; 1.2507x over previous
//
#include <hip/hip_runtime.h>

#define HH 192
#define WW 256
#define TH 8
#define TW 32
#define CCH 8            // channels per chunk (R11: 4->8, halves barriers)
#define NCHUNK 8         // 64 / 8
#define THREADS 576      // 9 waves; wave w handles i = w - 4
#define CHSTEP (CCH * HH * WW)

typedef float f4 __attribute__((ext_vector_type(4)));

// async global->LDS, 16B per lane, dest = wave-uniform base + lane*16
#define GLL(gp, lp) __builtin_amdgcn_global_load_lds(                        \
    (const __attribute__((address_space(1))) unsigned int*)(gp),            \
    (__attribute__((address_space(3))) unsigned int*)(lp), 16, 0, 0)

// smem layout (floats, linear in staged-unit order) — R8 geometry, CCH=8:
//   s1: [2 buf][8 ch][8 rows][32 cols]         =  4096 floats @ 0
//   s2: [2 buf][8 ch][16 rows][16 units x 16B] = 16384 floats @ 4096
// total 20480 floats = 80 KiB.
// Conflict ladder (measured): x2 stride-40 -> ~8 extra cyc/b128; stride-64
// -> ~4 (xv0 aligned=0, xv1/xv2 misaligned~6); fully-contiguous (x1) -> 0.
// R9 XOR swizzle and R10 DPP sharing both regressed — linear stride-64 + 3
// plain b128 reads is the measured local optimum for the read side.
__global__ __launch_bounds__(THREADS) void cost_volume_kernel(
    const float* __restrict__ x1, const float* __restrict__ x2,
    float* __restrict__ out)
{
    __shared__ __align__(16) float smem[20480];

    const int tid  = threadIdx.x;
    const int wave = tid >> 6;      // 0..8 -> i = wave - 4
    const int lane = tid & 63;
    const int r    = lane >> 3;     // 0..7 tile row
    const int wcg  = lane & 7;      // 0..7 col group (4 px each)

    const int bid = blockIdx.x;
    const int b   = bid / 192;      // 24 h-tiles * 8 w-tiles
    const int rem = bid % 192;
    const int h0  = (rem >> 3) * TH;
    const int w0  = (rem & 7) * TW;

    // ---- x2 staging: [8 ch][16 rows][16 units] = 2048 units = 32 strips ----
    // unit u: ch=u>>8, row=(u>>4)&15, cu=u&15 (col=cu*4; cu<=9 is data).
    // wave w does strips {w, w+9, w+18} and {w+27 if w<5}.
    auto desc2 = [&](int u, bool& v, int& goff) {
        const int ch = u >> 8, row = (u >> 4) & 15, cu = u & 15;
        const int hg = h0 - 4 + row, wg = w0 - 4 + cu * 4;
        v = (cu <= 9) & (hg >= 0) & (hg < HH) & (wg >= 0) & (wg <= WW - 4);
        goff = ((b * 64 + ch) * HH + hg) * WW + wg;
    };
    const int sA = wave, sB = wave + 9, sC = wave + 18, sD = wave + 27;
    bool vA, vB, vC, vD0; int gA, gB, gC, gD;
    desc2((sA << 6) + lane, vA, gA);
    desc2((sB << 6) + lane, vB, gB);
    desc2((sC << 6) + lane, vC, gC);
    desc2(((sD & 31) << 6) + lane, vD0, gD);
    const bool vD = vD0 & (wave < 5);

    // ---- x1 staging: [8 ch][8 rows][8 units] = 512 units = 8 strips ----
    // wave w<8 does strip w. Lane->dword fully linear: measured 0 conflicts.
    const bool v1 = (wave < 8);
    const int u1 = ((wave & 7) << 6) + lane;
    const int ch1 = u1 >> 6, r1 = (u1 >> 3) & 7, c1 = (u1 & 7) * 4;
    const int g1 = ((b * 64 + ch1) * HH + (h0 + r1)) * WW + (w0 + c1);

    auto issue = [&](int nb, int n) {
        const int cofs = n * CHSTEP;
        float* const b2 = smem + 4096 + nb * 8192;
        float* const b1 = smem + nb * 2048;
        if (vA) GLL(x2 + gA + cofs, b2 + (sA << 8));
        if (vB) GLL(x2 + gB + cofs, b2 + (sB << 8));
        if (vC) GLL(x2 + gC + cofs, b2 + (sC << 8));
        if (vD) GLL(x2 + gD + cofs, b2 + (sD << 8));
        if (v1) GLL(x1 + g1 + cofs, b1 + ((wave & 7) << 8));
    };

    // ---- pre-zero LDS: pad/OOB slots are never written by masked lanes ----
    const f4 z4 = {0.f, 0.f, 0.f, 0.f};
    for (int z = tid; z < 20480 / 4; z += THREADS) ((f4*)smem)[z] = z4;
    __syncthreads();

    issue(0, 0);
    __syncthreads();   // drains vmcnt(0) before s_barrier

    f4 acc0 = z4, acc1 = z4, acc2 = z4, acc3 = z4, acc4 = z4,
       acc5 = z4, acc6 = z4, acc7 = z4, acc8 = z4;

    const int row2 = r + 8 - wave;   // x2 halo row, in [0,15]

    for (int n = 0; n < NCHUNK; ++n) {
        if (n + 1 < NCHUNK) issue((n + 1) & 1, n + 1);
        const float* sb1 = smem + (n & 1) * 2048 + r * 32 + wcg * 4;
        const float* sb2 = smem + 4096 + (n & 1) * 8192 + row2 * 64 + wcg * 4;
#pragma unroll
        for (int cc = 0; cc < CCH; ++cc) {
            const f4 av  = *(const f4*)(sb1 + cc * 256);
            const f4 xv0 = *(const f4*)(sb2 + cc * 1024);
            const f4 xv1 = *(const f4*)(sb2 + cc * 1024 + 4);
            const f4 xv2 = *(const f4*)(sb2 + cc * 1024 + 8);
            // out px p needs halo col wcg*4 + p + 8 - jj  (p=0..3)
            const f4 w8 = xv0;
            const f4 w7 = __builtin_shufflevector(xv0, xv1, 1, 2, 3, 4);
            const f4 w6 = __builtin_shufflevector(xv0, xv1, 2, 3, 4, 5);
            const f4 w5 = __builtin_shufflevector(xv0, xv1, 3, 4, 5, 6);
            const f4 w4 = xv1;
            const f4 w3 = __builtin_shufflevector(xv1, xv2, 1, 2, 3, 4);
            const f4 w2 = __builtin_shufflevector(xv1, xv2, 2, 3, 4, 5);
            const f4 w1w = __builtin_shufflevector(xv1, xv2, 3, 4, 5, 6);
            const f4 w0w = xv2;
            acc0 = __builtin_elementwise_fma(av, w0w, acc0);
            acc1 = __builtin_elementwise_fma(av, w1w, acc1);
            acc2 = __builtin_elementwise_fma(av, w2, acc2);
            acc3 = __builtin_elementwise_fma(av, w3, acc3);
            acc4 = __builtin_elementwise_fma(av, w4, acc4);
            acc5 = __builtin_elementwise_fma(av, w5, acc5);
            acc6 = __builtin_elementwise_fma(av, w6, acc6);
            acc7 = __builtin_elementwise_fma(av, w7, acc7);
            acc8 = __builtin_elementwise_fma(av, w8, acc8);
        }
        __syncthreads();
    }

    // ---- epilogue ----
    const float scale = 1.0f / 81.0f;
    const int hout = h0 + r;
    const int wout = w0 + wcg * 4;
    // k = (9*i + j) mod 81 = (9*wave + jj + 41) mod 81
#define CV_OUT(JJ)                                                           \
    {                                                                        \
        const int k = (9 * wave + (JJ) + 41) % 81;                           \
        float* po = out + ((b * 81 + k) * HH + hout) * WW + wout;            \
        *(f4*)po = acc##JJ * scale;                                          \
    }
    CV_OUT(0) CV_OUT(1) CV_OUT(2) CV_OUT(3) CV_OUT(4)
    CV_OUT(5) CV_OUT(6) CV_OUT(7) CV_OUT(8)
#undef CV_OUT
}

extern "C" void kernel_launch(void* const* d_in, const int* in_sizes, int n_in,
                              void* d_out, int out_size, void* d_ws, size_t ws_size,
                              hipStream_t stream) {
    const float* x1 = (const float*)d_in[0];
    const float* x2 = (const float*)d_in[1];
    float* out = (float*)d_out;
    dim3 grid(8 * 24 * 8);   // 1536 blocks
    dim3 block(THREADS);
    hipLaunchKernelGGL(cost_volume_kernel, grid, block, 0, stream, x1, x2, out);
}